// Round 7
// baseline (2156.480 us; speedup 1.0000x reference)
//
#include <hip/hip_runtime.h>
#include <hip/hip_fp16.h>
#include <math.h>

#define NH 8
#define NDIST 513
#define NBLK 512
#define NTHR 256
#define BARSTRIDE 4096   // uints per barrier record

union H8 { uint4 u4; __half2 h2[4]; };

// ---- two-level distributed grid barrier (single-use counters, memset-reset) ----
// layout per barrier (uints): sub s at [s*64] (16 subs, 256B apart), master at
// [1024], mirror m at [1088 + m*64]. 512 blocks = 16 subs x 32 arrivals.
__device__ __forceinline__ void gbar(unsigned* base, int bid) {
  __syncthreads();
  __threadfence();   // release: prior global writes visible device-wide
  if (threadIdx.x == 0) {
    int s = bid & 15;
    unsigned old = __hip_atomic_fetch_add(base + s * 64, 1u, __ATOMIC_ACQ_REL,
                                          __HIP_MEMORY_SCOPE_AGENT);
    if (old == 31u) {  // last arrival on this sub-line
      unsigned m = __hip_atomic_fetch_add(base + 1024, 1u, __ATOMIC_ACQ_REL,
                                          __HIP_MEMORY_SCOPE_AGENT);
      if (m == 15u) {  // last sub: release everyone via 16 mirror lines
        #pragma unroll
        for (int i = 0; i < 16; ++i)
          __hip_atomic_store(base + 1088 + i * 64, 1u, __ATOMIC_RELEASE,
                             __HIP_MEMORY_SCOPE_AGENT);
      }
    }
    while (__hip_atomic_load(base + 1088 + s * 64, __ATOMIC_ACQUIRE,
                             __HIP_MEMORY_SCOPE_AGENT) == 0u)
      __builtin_amdgcn_s_sleep(32);   // ~2048 cyc between polls, 32 pollers/line
  }
  __syncthreads();
  __threadfence();   // acquire side
}

// ---- 4 rows x 256 cols x 256 k GEMM partials (64cg x 4ks), red = [ks][r][c] ----
__device__ __forceinline__ void gemm4(const float4* __restrict__ w0, int ld4,
                                      const float* ldsA, float* red, int tid) {
  int cg = tid & 63, ks = tid >> 6;
  const float4* w = w0 + (ks * 64) * ld4 + cg;
  float a00=0,a01=0,a02=0,a03=0, a10=0,a11=0,a12=0,a13=0,
        a20=0,a21=0,a22=0,a23=0, a30=0,a31=0,a32=0,a33=0;
  const float* A = ldsA + ks * 64;
  #pragma unroll 4
  for (int kk = 0; kk < 64; ++kk) {
    float4 b4 = w[kk * ld4];
    float x0 = A[kk], x1 = A[256 + kk], x2 = A[512 + kk], x3 = A[768 + kk];
    a00=fmaf(x0,b4.x,a00); a01=fmaf(x0,b4.y,a01); a02=fmaf(x0,b4.z,a02); a03=fmaf(x0,b4.w,a03);
    a10=fmaf(x1,b4.x,a10); a11=fmaf(x1,b4.y,a11); a12=fmaf(x1,b4.z,a12); a13=fmaf(x1,b4.w,a13);
    a20=fmaf(x2,b4.x,a20); a21=fmaf(x2,b4.y,a21); a22=fmaf(x2,b4.z,a22); a23=fmaf(x2,b4.w,a23);
    a30=fmaf(x3,b4.x,a30); a31=fmaf(x3,b4.y,a31); a32=fmaf(x3,b4.z,a32); a33=fmaf(x3,b4.w,a33);
  }
  float* rp = red + ks * 1024 + cg * 4;
  *(float4*)(rp)       = make_float4(a00,a01,a02,a03);
  *(float4*)(rp + 256) = make_float4(a10,a11,a12,a13);
  *(float4*)(rp + 512) = make_float4(a20,a21,a22,a23);
  *(float4*)(rp + 768) = make_float4(a30,a31,a32,a33);
}

__device__ __forceinline__ float redsum(const float* red, int r, int c) {
  return red[r*256+c] + red[1024 + r*256+c] + red[2048 + r*256+c] + red[3072 + r*256+c];
}

__device__ __forceinline__ void ln_write(float val, float* red2, float* dst, int tid) {
  float ss = val;
  #pragma unroll
  for (int sh = 32; sh >= 1; sh >>= 1) ss += __shfl_xor(ss, sh);
  if ((tid & 63) == 0) red2[tid >> 6] = ss;
  __syncthreads();
  float mean = (red2[0] + red2[1] + red2[2] + red2[3]) * (1.f / 256.f);
  float d = val - mean;
  float s2 = d * d;
  __syncthreads();
  #pragma unroll
  for (int sh = 32; sh >= 1; sh >>= 1) s2 += __shfl_xor(s2, sh);
  if ((tid & 63) == 0) red2[tid >> 6] = s2;
  __syncthreads();
  float var = (red2[0] + red2[1] + red2[2] + red2[3]) * (1.f / 256.f);
  dst[tid] = d * rsqrtf(var + 1e-5f);
}

__global__ __launch_bounds__(NTHR, 2) void k_mega(
    const float* __restrict__ x, const int* __restrict__ pos_s,
    const int* __restrict__ pos_e, const int* __restrict__ real_lengths,
    const int* __restrict__ lex_num, const float* __restrict__ pe,
    const float* __restrict__ W_fus, const float* __restrict__ b_fus,
    const float* __restrict__ Wq, const float* __restrict__ bq,
    const float* __restrict__ Wk, const float* __restrict__ bk,
    const float* __restrict__ Wv, const float* __restrict__ bv,
    const float* __restrict__ Wr, const float* __restrict__ uvec,
    const float* __restrict__ vvec, const float* __restrict__ W1,
    const float* __restrict__ b1, const float* __restrict__ W2,
    const float* __restrict__ b2, float* __restrict__ out,
    __half* __restrict__ Tt, float* __restrict__ QU, float* __restrict__ QV,
    float* __restrict__ Kb, float* __restrict__ Vb, __half* __restrict__ P,
    float* __restrict__ Y, float* __restrict__ C1,
    float* __restrict__ H1, float* __restrict__ Pb, unsigned* __restrict__ bar) {
  __shared__ __align__(16) float smem[8704];   // 34.8 KB (k_p stage high-water)
  const int tid = threadIdx.x;
  const int bid = blockIdx.x;
  const int lex = lex_num[0];
  int bc = 0;

  // ================= tables: Tt[g][d][c] (f16) =================
  for (int uu = bid; uu < 516; uu += NBLK) {
    int g = uu & 3, r0 = (uu >> 2) * 4;
    float* ldsA = smem; float* red = smem + 1024;
    #pragma unroll
    for (int t = 0; t < 4; ++t) {
      int idx = t * 256 + tid, r = idx >> 8, c = idx & 255;
      int row = r0 + r;
      ldsA[idx] = (row < NDIST) ? pe[row * 256 + c] : 0.f;
    }
    __syncthreads();
    gemm4((const float4*)(W_fus + g * 65536), 64, ldsA, red, tid);
    __syncthreads();
    float bb = (g == 0) ? b_fus[tid] : 0.f;
    #pragma unroll
    for (int r = 0; r < 4; ++r) {
      int row = r0 + r;
      if (row < NDIST)
        Tt[(g * NDIST + row) * 256 + tid] = __float2half(bb + redsum(red, r, tid));
    }
    __syncthreads();
  }
  gbar(bar + (bc++) * BARSTRIDE, bid);

  for (int l = 0; l < 2; ++l) {
    const float* cur = l ? C1 : x;
    float* outb = l ? out : C1;
    const float* wq = Wq + l * 65536; const float* wk = Wk + l * 65536;
    const float* wv = Wv + l * 65536; const float* wr = Wr + l * 65536;
    const float* w1 = W1 + l * 262144; const float* w2 = W2 + l * 262144;
    const float* bql = bq + l * 256; const float* bkl = bk + l * 256;
    const float* bvl = bv + l * 256; const float* b1l = b1 + l * 1024;
    const float* b2l = b2 + l * 256; const float* ul = uvec + l * 256;
    const float* vl = vvec + l * 256;

    // ================= proj: q(->QU,QV), k, v : 384 units =================
    for (int uu = bid; uu < 384; uu += NBLK) {
      int by = uu / 128, rt = uu % 128, r0 = rt * 4;
      const float* W = (by == 0) ? wq : (by == 1) ? wk : wv;
      float* ldsA = smem; float* red = smem + 1024;
      #pragma unroll
      for (int t = 0; t < 4; ++t) {
        int idx = t * 256 + tid, r = idx >> 8, c = idx & 255;
        ldsA[idx] = cur[(r0 + r) * 256 + c];
      }
      __syncthreads();
      gemm4((const float4*)W, 64, ldsA, red, tid);
      __syncthreads();
      #pragma unroll
      for (int r = 0; r < 4; ++r) {
        int row = r0 + r;
        float s = redsum(red, r, tid);
        if (by == 0) {
          float base = s + bql[tid];
          QU[row * 256 + tid] = base + ul[tid];
          QV[row * 256 + tid] = base + vl[tid];
        } else if (by == 1) {
          Kb[row * 256 + tid] = s + bkl[tid];
        } else {
          Vb[row * 256 + tid] = s + bvl[tid];
        }
      }
      __syncthreads();
    }
    gbar(bar + (bc++) * BARSTRIDE, bid);

    // ================= P[bi][h*256+c] : 512 units (8h x 64 rowtiles of 8) ====
    for (int uu = bid; uu < 512; uu += NBLK) {
      int h = uu >> 6, r0 = (uu & 63) * 8;
      float* ldsB = smem;          // 32*257 = 8224
      float* ldsA = smem + 8224;   // 8*32 = 256 (ends 8480 <= 8704)
      #pragma unroll
      for (int pass = 0; pass < 8; ++pass) {
        int c = pass * 32 + (tid >> 3), q = tid & 7;
        float4 w4 = ((const float4*)(wr + c * 256 + h * 32))[q];
        ldsB[(q*4+0)*257 + c] = w4.x; ldsB[(q*4+1)*257 + c] = w4.y;
        ldsB[(q*4+2)*257 + c] = w4.z; ldsB[(q*4+3)*257 + c] = w4.w;
      }
      { int r = tid >> 5, d = tid & 31; ldsA[r*32 + d] = QV[(r0 + r) * 256 + h*32 + d]; }
      __syncthreads();
      int c = tid;
      float acc[8] = {0,0,0,0,0,0,0,0};
      #pragma unroll 4
      for (int d = 0; d < 32; ++d) {
        float b = ldsB[d*257 + c];
        #pragma unroll
        for (int r = 0; r < 8; ++r) acc[r] = fmaf(ldsA[r*32 + d], b, acc[r]);
      }
      #pragma unroll
      for (int r = 0; r < 8; ++r) P[(r0 + r) * 2048 + h*256 + c] = __float2half(acc[r]);
      __syncthreads();
    }
    gbar(bar + (bc++) * BARSTRIDE, bid);

    // ====== fused score + softmax + AV + residual + LN : 512 units (per bi) ==
    for (int uu = bid; uu < 512; uu += NBLK) {
      int bi = uu, b = bi >> 8, i = bi & 255;
      int rl = real_lengths[b] + lex;
      float* sc    = smem;                     // 2048
      __half* plh  = (__half*)(smem + 2048);   // 2048 halfs (1024 f32)
      float* qu    = smem + 3072;              // 256
      float* part  = smem + 3328;              // 1024
      float* inv8  = smem + 4352;              // 8
      float* red2  = smem + 4360;              // 4
      float* scl   = smem + 4368;              // 256
      #pragma unroll
      for (int t = 0; t < 8; ++t) sc[t * 256 + tid] = -1e15f;
      ((uint4*)plh)[tid] = ((const uint4*)(P + bi * 2048))[tid];
      qu[tid] = QU[bi * 256 + tid];
      __syncthreads();
      int psi = pos_s[b*256 + i], pei = pos_e[b*256 + i];
      int jl = tid >> 3, cl = tid & 7;
      int nchunk = (rl + 31) >> 5;
      for (int jc = 0; jc < nchunk; ++jc) {
        int j = jc * 32 + jl;
        int psj = pos_s[b*256 + j], pej = pos_e[b*256 + j];
        const __half* t0 = Tt + (psi - psj + 256) * 256;
        const __half* t1 = Tt + (NDIST   + (psi - pej + 256)) * 256;
        const __half* t2 = Tt + (2*NDIST + (pei - psj + 256)) * 256;
        const __half* t3 = Tt + (3*NDIST + (pei - pej + 256)) * 256;
        __half2 z2 = __float2half2_rn(0.f);
        __half2 acc2[NH];
        #pragma unroll
        for (int h = 0; h < NH; ++h) acc2[h] = z2;
        #pragma unroll
        for (int ci = 0; ci < 4; ++ci) {
          int c0 = (ci * 8 + cl) * 8;
          H8 A0, A1, A2, A3;
          A0.u4 = *(const uint4*)(t0 + c0);
          A1.u4 = *(const uint4*)(t1 + c0);
          A2.u4 = *(const uint4*)(t2 + c0);
          A3.u4 = *(const uint4*)(t3 + c0);
          __half2 r2[4];
          #pragma unroll
          for (int p = 0; p < 4; ++p) {
            __half2 s = __hadd2(__hadd2(A0.h2[p], A1.h2[p]), __hadd2(A2.h2[p], A3.h2[p]));
            r2[p] = __hmul2(s, __hgt2(s, z2));
          }
          #pragma unroll
          for (int h = 0; h < NH; ++h) {
            H8 Ph;
            Ph.u4 = *(const uint4*)(plh + h*256 + c0);
            #pragma unroll
            for (int p = 0; p < 4; ++p) acc2[h] = __hfma2(r2[p], Ph.h2[p], acc2[h]);
          }
        }
        const float4* kp = (const float4*)(Kb + (b*256 + j) * 256);
        float bd[NH];
        #pragma unroll
        for (int h = 0; h < NH; ++h) {
          bd[h] = __low2float(acc2[h]) + __high2float(acc2[h]);
          float4 k4 = kp[h*8 + cl];
          float4 q4 = *(const float4*)(qu + h*32 + cl*4);
          bd[h] += k4.x*q4.x + k4.y*q4.y + k4.z*q4.z + k4.w*q4.w;
        }
        #pragma unroll
        for (int h = 0; h < NH; ++h) {
          bd[h] += __shfl_xor(bd[h], 1);
          bd[h] += __shfl_xor(bd[h], 2);
          bd[h] += __shfl_xor(bd[h], 4);
        }
        if (cl == 0) {
          #pragma unroll
          for (int h = 0; h < NH; ++h) scl[h*32 + jl] = bd[h];
        }
        __syncthreads();
        { int h = tid >> 5, jj = tid & 31, j2 = jc * 32 + jj;
          if (j2 < rl) sc[h*256 + j2] = scl[h*32 + jj]; }
        __syncthreads();
      }
      // softmax
      {
        int h = tid >> 5, t = tid & 31;
        float mx = -INFINITY;
        #pragma unroll
        for (int m = 0; m < 8; ++m) mx = fmaxf(mx, sc[h*256 + t + 32*m]);
        #pragma unroll
        for (int sh = 16; sh >= 1; sh >>= 1) mx = fmaxf(mx, __shfl_xor(mx, sh));
        float sum = 0.f;
        #pragma unroll
        for (int m = 0; m < 8; ++m) {
          float e = __expf(sc[h*256 + t + 32*m] - mx);
          sc[h*256 + t + 32*m] = e;
          sum += e;
        }
        #pragma unroll
        for (int sh = 16; sh >= 1; sh >>= 1) sum += __shfl_xor(sum, sh);
        if (t == 0) inv8[h] = 1.f / sum;
      }
      __syncthreads();
      // AV
      {
        int n4 = tid & 63, jg = tid >> 6, h = n4 >> 3;
        float4 acc = make_float4(0.f, 0.f, 0.f, 0.f);
        if (jg * 64 < rl) {
          const float4* vp = (const float4*)(Vb + b * 65536) + n4;
          #pragma unroll 4
          for (int jj0 = 0; jj0 < 64; ++jj0) {
            int jj = jg * 64 + jj0;
            float s = sc[h*256 + jj];
            float4 v4 = vp[jj * 64];
            acc.x = fmaf(s, v4.x, acc.x); acc.y = fmaf(s, v4.y, acc.y);
            acc.z = fmaf(s, v4.z, acc.z); acc.w = fmaf(s, v4.w, acc.w);
          }
        }
        *(float4*)(part + jg*256 + n4*4) = acc;
      }
      __syncthreads();
      int n = tid;
      float o = part[n] + part[256+n] + part[512+n] + part[768+n];
      float val = cur[bi*256 + n] + o * inv8[n >> 5];
      ln_write(val, red2, Y + bi*256, tid);
      __syncthreads();
    }
    gbar(bar + (bc++) * BARSTRIDE, bid);

    // ================= ffn1: 512 units (128 rt4 x 4 colchunks) ==============
    for (int uu = bid; uu < 512; uu += NBLK) {
      int rt = uu >> 2, cc = uu & 3, r0 = rt * 4;
      float* ldsA = smem; float* red = smem + 1024;
      #pragma unroll
      for (int t = 0; t < 4; ++t) {
        int idx = t * 256 + tid, r = idx >> 8, c = idx & 255;
        ldsA[idx] = Y[(r0 + r) * 256 + c];
      }
      __syncthreads();
      gemm4((const float4*)w1 + cc * 64, 256, ldsA, red, tid);
      __syncthreads();
      int n = cc * 256 + tid;
      float bb = b1l[n];
      #pragma unroll
      for (int r = 0; r < 4; ++r)
        H1[(r0 + r) * 1024 + n] = fmaxf(bb + redsum(red, r, tid), 0.f);
      __syncthreads();
    }
    gbar(bar + (bc++) * BARSTRIDE, bid);

    // ================= ffn2 partials: 512 units (128 rt4 x 4 kchunks) =======
    for (int uu = bid; uu < 512; uu += NBLK) {
      int rt = uu >> 2, kc = uu & 3, r0 = rt * 4, k0 = kc * 256;
      float* ldsA = smem; float* red = smem + 1024;
      #pragma unroll
      for (int t = 0; t < 4; ++t) {
        int idx = t * 256 + tid, r = idx >> 8, c = idx & 255;
        ldsA[idx] = H1[(r0 + r) * 1024 + k0 + c];
      }
      __syncthreads();
      gemm4((const float4*)(w2 + k0 * 256), 64, ldsA, red, tid);
      __syncthreads();
      #pragma unroll
      for (int r = 0; r < 4; ++r)
        Pb[kc * 131072 + (r0 + r) * 256 + tid] = redsum(red, r, tid);
      __syncthreads();
    }
    gbar(bar + (bc++) * BARSTRIDE, bid);

    // ================= ffn2 reduce + relu + residual + LN : 512 units =======
    for (int uu = bid; uu < 512; uu += NBLK) {
      int m = uu;
      float* red2 = smem;
      float s = Pb[m*256 + tid] + Pb[131072 + m*256 + tid] +
                Pb[262144 + m*256 + tid] + Pb[393216 + m*256 + tid] + b2l[tid];
      float val = fmaxf(s, 0.f) + Y[m*256 + tid];
      ln_write(val, red2, outb + m*256, tid);
      __syncthreads();
    }
    gbar(bar + (bc++) * BARSTRIDE, bid);
  }
}

extern "C" void kernel_launch(void* const* d_in, const int* in_sizes, int n_in,
                              void* d_out, int out_size, void* d_ws, size_t ws_size,
                              hipStream_t stream) {
  const float* x            = (const float*)d_in[0];
  const int*   pos_s        = (const int*)d_in[1];
  const int*   pos_e        = (const int*)d_in[2];
  const int*   real_lengths = (const int*)d_in[3];
  const int*   lex_num      = (const int*)d_in[4];
  const float* pe           = (const float*)d_in[5];
  const float* W_fus        = (const float*)d_in[6];
  const float* b_fus        = (const float*)d_in[7];
  const float* Wq           = (const float*)d_in[8];
  const float* bq           = (const float*)d_in[9];
  const float* Wk           = (const float*)d_in[10];
  const float* bk           = (const float*)d_in[11];
  const float* Wv           = (const float*)d_in[12];
  const float* bv           = (const float*)d_in[13];
  const float* Wr           = (const float*)d_in[14];
  // br dropped: per-(b,i,h) constant score shift, softmax-invariant
  const float* u            = (const float*)d_in[16];
  const float* v            = (const float*)d_in[17];
  const float* W1           = (const float*)d_in[18];
  const float* b1           = (const float*)d_in[19];
  const float* W2           = (const float*)d_in[20];
  const float* b2           = (const float*)d_in[21];
  float* out = (float*)d_out;

  unsigned* bar = (unsigned*)d_ws;        // 16 barriers x 4096 uints = 256 KB
  float* base = (float*)d_ws + 16 * BARSTRIDE;
  __half* Tt = (__half*)base;             // 4*513*256 halfs = 262656 f32
  float* QU  = base + 262656;
  float* QV  = QU + 131072;
  float* Kb  = QV + 131072;
  float* Vb  = Kb + 131072;
  __half* P  = (__half*)(Vb + 131072);    // 512*2048 halfs = 524288 f32
  float* Y   = Vb + 131072 + 524288;
  float* C1  = Y + 131072;
  float* H1  = C1 + 131072;               // 524288
  float* Pb  = H1 + 524288;               // 524288

  hipMemsetAsync(bar, 0, 16 * BARSTRIDE * sizeof(unsigned), stream);
  k_mega<<<NBLK, NTHR, 0, stream>>>(x, pos_s, pos_e, real_lengths, lex_num, pe,
      W_fus, b_fus, Wq, bq, Wk, bk, Wv, bv, Wr, u, v, W1, b1, W2, b2, out,
      Tt, QU, QV, Kb, Vb, P, Y, C1, H1, Pb, bar);
}

// Round 8
// 411.456 us; speedup vs baseline: 5.2411x; 5.2411x over previous
//
#include <hip/hip_runtime.h>
#include <hip/hip_fp16.h>
#include <math.h>

#define NH 8
#define NDIST 513
#define NBLK 512
#define NTHR 256
#define BARSTRIDE 4096   // uints per barrier record

union H8 { uint4 u4; __half2 h2[4]; };

// ---- two-level grid barrier, RELAXED spin (no per-poll cache maintenance) ----
// Per barrier (uints): sub s at [s*64] (16 lines), master at [1024],
// mirror m at [1088 + m*64]. 512 blocks = 16 subs x 32 arrivals.
// Key fix vs r6/r7: polling with ACQUIRE emitted buffer_inv (L1+L2 cache-wide
// invalidate) per poll -> invalidation storm poisoned all compute. Poll RELAXED;
// exactly one release fence before arrival and one acquire fence after exit.
__device__ __forceinline__ void gbar(unsigned* base, int bid) {
  __syncthreads();                 // block's stores drained to L2 (release per-wave)
  if (threadIdx.x == 0) {
    __threadfence();               // single release: writeback this XCD's L2
    int s = bid & 15;
    unsigned old = __hip_atomic_fetch_add(base + s * 64, 1u, __ATOMIC_RELAXED,
                                          __HIP_MEMORY_SCOPE_AGENT);
    if (old == 31u) {              // last arrival on this sub-line
      unsigned m = __hip_atomic_fetch_add(base + 1024, 1u, __ATOMIC_RELAXED,
                                          __HIP_MEMORY_SCOPE_AGENT);
      if (m == 15u) {              // last sub: release via 16 mirror lines
        #pragma unroll
        for (int i = 0; i < 16; ++i)
          __hip_atomic_store(base + 1088 + i * 64, 1u, __ATOMIC_RELAXED,
                             __HIP_MEMORY_SCOPE_AGENT);
      }
    }
    while (__hip_atomic_load(base + 1088 + s * 64, __ATOMIC_RELAXED,
                             __HIP_MEMORY_SCOPE_AGENT) == 0u)
      __builtin_amdgcn_s_sleep(16);
    __threadfence();               // single acquire: invalidate stale L1/L2 lines
  }
  __syncthreads();
}

// ---- 4 rows x 256 cols x 256 k GEMM partials (64cg x 4ks), red = [ks][r][c] ----
__device__ __forceinline__ void gemm4(const float4* __restrict__ w0, int ld4,
                                      const float* ldsA, float* red, int tid) {
  int cg = tid & 63, ks = tid >> 6;
  const float4* w = w0 + (ks * 64) * ld4 + cg;
  float a00=0,a01=0,a02=0,a03=0, a10=0,a11=0,a12=0,a13=0,
        a20=0,a21=0,a22=0,a23=0, a30=0,a31=0,a32=0,a33=0;
  const float* A = ldsA + ks * 64;
  #pragma unroll 4
  for (int kk = 0; kk < 64; ++kk) {
    float4 b4 = w[kk * ld4];
    float x0 = A[kk], x1 = A[256 + kk], x2 = A[512 + kk], x3 = A[768 + kk];
    a00=fmaf(x0,b4.x,a00); a01=fmaf(x0,b4.y,a01); a02=fmaf(x0,b4.z,a02); a03=fmaf(x0,b4.w,a03);
    a10=fmaf(x1,b4.x,a10); a11=fmaf(x1,b4.y,a11); a12=fmaf(x1,b4.z,a12); a13=fmaf(x1,b4.w,a13);
    a20=fmaf(x2,b4.x,a20); a21=fmaf(x2,b4.y,a21); a22=fmaf(x2,b4.z,a22); a23=fmaf(x2,b4.w,a23);
    a30=fmaf(x3,b4.x,a30); a31=fmaf(x3,b4.y,a31); a32=fmaf(x3,b4.z,a32); a33=fmaf(x3,b4.w,a33);
  }
  float* rp = red + ks * 1024 + cg * 4;
  *(float4*)(rp)       = make_float4(a00,a01,a02,a03);
  *(float4*)(rp + 256) = make_float4(a10,a11,a12,a13);
  *(float4*)(rp + 512) = make_float4(a20,a21,a22,a23);
  *(float4*)(rp + 768) = make_float4(a30,a31,a32,a33);
}

__device__ __forceinline__ float redsum(const float* red, int r, int c) {
  return red[r*256+c] + red[1024 + r*256+c] + red[2048 + r*256+c] + red[3072 + r*256+c];
}

__device__ __forceinline__ void ln_write(float val, float* red2, float* dst, int tid) {
  float ss = val;
  #pragma unroll
  for (int sh = 32; sh >= 1; sh >>= 1) ss += __shfl_xor(ss, sh);
  if ((tid & 63) == 0) red2[tid >> 6] = ss;
  __syncthreads();
  float mean = (red2[0] + red2[1] + red2[2] + red2[3]) * (1.f / 256.f);
  float d = val - mean;
  float s2 = d * d;
  __syncthreads();
  #pragma unroll
  for (int sh = 32; sh >= 1; sh >>= 1) s2 += __shfl_xor(s2, sh);
  if ((tid & 63) == 0) red2[tid >> 6] = s2;
  __syncthreads();
  float var = (red2[0] + red2[1] + red2[2] + red2[3]) * (1.f / 256.f);
  dst[tid] = d * rsqrtf(var + 1e-5f);
}

__global__ __launch_bounds__(NTHR, 2) void k_mega(
    const float* __restrict__ x, const int* __restrict__ pos_s,
    const int* __restrict__ pos_e, const int* __restrict__ real_lengths,
    const int* __restrict__ lex_num, const float* __restrict__ pe,
    const float* __restrict__ W_fus, const float* __restrict__ b_fus,
    const float* __restrict__ Wq, const float* __restrict__ bq,
    const float* __restrict__ Wk, const float* __restrict__ bk,
    const float* __restrict__ Wv, const float* __restrict__ bv,
    const float* __restrict__ Wr, const float* __restrict__ uvec,
    const float* __restrict__ vvec, const float* __restrict__ W1,
    const float* __restrict__ b1, const float* __restrict__ W2,
    const float* __restrict__ b2, float* __restrict__ out,
    __half* __restrict__ Tt, float* __restrict__ QU, float* __restrict__ QV,
    float* __restrict__ Kb, float* __restrict__ Vb, __half* __restrict__ P,
    float* __restrict__ Y, float* __restrict__ C1,
    float* __restrict__ H1, float* __restrict__ Pb, unsigned* __restrict__ bar) {
  __shared__ __align__(16) float smem[8704];
  const int tid = threadIdx.x;
  const int bid = blockIdx.x;
  const int lex = lex_num[0];
  int bc = 0;

  // ================= tables: Tt[g][d][c] (f16) =================
  for (int uu = bid; uu < 516; uu += NBLK) {
    int g = uu & 3, r0 = (uu >> 2) * 4;
    float* ldsA = smem; float* red = smem + 1024;
    #pragma unroll
    for (int t = 0; t < 4; ++t) {
      int idx = t * 256 + tid, r = idx >> 8, c = idx & 255;
      int row = r0 + r;
      ldsA[idx] = (row < NDIST) ? pe[row * 256 + c] : 0.f;
    }
    __syncthreads();
    gemm4((const float4*)(W_fus + g * 65536), 64, ldsA, red, tid);
    __syncthreads();
    float bb = (g == 0) ? b_fus[tid] : 0.f;
    #pragma unroll
    for (int r = 0; r < 4; ++r) {
      int row = r0 + r;
      if (row < NDIST)
        Tt[(g * NDIST + row) * 256 + tid] = __float2half(bb + redsum(red, r, tid));
    }
    __syncthreads();
  }
  gbar(bar + (bc++) * BARSTRIDE, bid);

  for (int l = 0; l < 2; ++l) {
    const float* cur = l ? C1 : x;
    float* outb = l ? out : C1;
    const float* wq = Wq + l * 65536; const float* wk = Wk + l * 65536;
    const float* wv = Wv + l * 65536; const float* wr = Wr + l * 65536;
    const float* w1 = W1 + l * 262144; const float* w2 = W2 + l * 262144;
    const float* bql = bq + l * 256; const float* bkl = bk + l * 256;
    const float* bvl = bv + l * 256; const float* b1l = b1 + l * 1024;
    const float* b2l = b2 + l * 256; const float* ul = uvec + l * 256;
    const float* vl = vvec + l * 256;

    // ================= proj: q(->QU,QV), k, v : 384 units =================
    for (int uu = bid; uu < 384; uu += NBLK) {
      int by = uu / 128, rt = uu % 128, r0 = rt * 4;
      const float* W = (by == 0) ? wq : (by == 1) ? wk : wv;
      float* ldsA = smem; float* red = smem + 1024;
      #pragma unroll
      for (int t = 0; t < 4; ++t) {
        int idx = t * 256 + tid, r = idx >> 8, c = idx & 255;
        ldsA[idx] = cur[(r0 + r) * 256 + c];
      }
      __syncthreads();
      gemm4((const float4*)W, 64, ldsA, red, tid);
      __syncthreads();
      #pragma unroll
      for (int r = 0; r < 4; ++r) {
        int row = r0 + r;
        float s = redsum(red, r, tid);
        if (by == 0) {
          float base = s + bql[tid];
          QU[row * 256 + tid] = base + ul[tid];
          QV[row * 256 + tid] = base + vl[tid];
        } else if (by == 1) {
          Kb[row * 256 + tid] = s + bkl[tid];
        } else {
          Vb[row * 256 + tid] = s + bvl[tid];
        }
      }
      __syncthreads();
    }
    gbar(bar + (bc++) * BARSTRIDE, bid);

    // ================= P[bi][h*256+c] : 512 units (8h x 64 rowtiles of 8) ====
    for (int uu = bid; uu < 512; uu += NBLK) {
      int h = uu >> 6, r0 = (uu & 63) * 8;
      float* ldsB = smem;          // 32*257 = 8224
      float* ldsA = smem + 8224;   // 8*32 = 256
      #pragma unroll
      for (int pass = 0; pass < 8; ++pass) {
        int c = pass * 32 + (tid >> 3), q = tid & 7;
        float4 w4 = ((const float4*)(wr + c * 256 + h * 32))[q];
        ldsB[(q*4+0)*257 + c] = w4.x; ldsB[(q*4+1)*257 + c] = w4.y;
        ldsB[(q*4+2)*257 + c] = w4.z; ldsB[(q*4+3)*257 + c] = w4.w;
      }
      { int r = tid >> 5, d = tid & 31; ldsA[r*32 + d] = QV[(r0 + r) * 256 + h*32 + d]; }
      __syncthreads();
      int c = tid;
      float acc[8] = {0,0,0,0,0,0,0,0};
      #pragma unroll 4
      for (int d = 0; d < 32; ++d) {
        float b = ldsB[d*257 + c];
        #pragma unroll
        for (int r = 0; r < 8; ++r) acc[r] = fmaf(ldsA[r*32 + d], b, acc[r]);
      }
      #pragma unroll
      for (int r = 0; r < 8; ++r) P[(r0 + r) * 2048 + h*256 + c] = __float2half(acc[r]);
      __syncthreads();
    }
    gbar(bar + (bc++) * BARSTRIDE, bid);

    // ====== fused score + softmax + AV + residual + LN : 512 units (per bi) ==
    for (int uu = bid; uu < 512; uu += NBLK) {
      int bi = uu, b = bi >> 8, i = bi & 255;
      int rl = real_lengths[b] + lex;
      float* sc    = smem;                     // 2048
      __half* plh  = (__half*)(smem + 2048);   // 2048 halfs
      float* qu    = smem + 3072;              // 256
      float* part  = smem + 3328;              // 1024
      float* inv8  = smem + 4352;              // 8
      float* red2  = smem + 4360;              // 4
      float* scl   = smem + 4368;              // 256
      #pragma unroll
      for (int t = 0; t < 8; ++t) sc[t * 256 + tid] = -1e15f;
      ((uint4*)plh)[tid] = ((const uint4*)(P + bi * 2048))[tid];
      qu[tid] = QU[bi * 256 + tid];
      __syncthreads();
      int psi = pos_s[b*256 + i], pei = pos_e[b*256 + i];
      int jl = tid >> 3, cl = tid & 7;
      int nchunk = (rl + 31) >> 5;
      for (int jc = 0; jc < nchunk; ++jc) {
        int j = jc * 32 + jl;
        int psj = pos_s[b*256 + j], pej = pos_e[b*256 + j];
        const __half* t0 = Tt + (psi - psj + 256) * 256;
        const __half* t1 = Tt + (NDIST   + (psi - pej + 256)) * 256;
        const __half* t2 = Tt + (2*NDIST + (pei - psj + 256)) * 256;
        const __half* t3 = Tt + (3*NDIST + (pei - pej + 256)) * 256;
        __half2 z2 = __float2half2_rn(0.f);
        __half2 acc2[NH];
        #pragma unroll
        for (int h = 0; h < NH; ++h) acc2[h] = z2;
        #pragma unroll
        for (int ci = 0; ci < 4; ++ci) {
          int c0 = (ci * 8 + cl) * 8;
          H8 A0, A1, A2, A3;
          A0.u4 = *(const uint4*)(t0 + c0);
          A1.u4 = *(const uint4*)(t1 + c0);
          A2.u4 = *(const uint4*)(t2 + c0);
          A3.u4 = *(const uint4*)(t3 + c0);
          __half2 r2[4];
          #pragma unroll
          for (int p = 0; p < 4; ++p) {
            __half2 s = __hadd2(__hadd2(A0.h2[p], A1.h2[p]), __hadd2(A2.h2[p], A3.h2[p]));
            r2[p] = __hmul2(s, __hgt2(s, z2));
          }
          #pragma unroll
          for (int h = 0; h < NH; ++h) {
            H8 Ph;
            Ph.u4 = *(const uint4*)(plh + h*256 + c0);
            #pragma unroll
            for (int p = 0; p < 4; ++p) acc2[h] = __hfma2(r2[p], Ph.h2[p], acc2[h]);
          }
        }
        const float4* kp = (const float4*)(Kb + (b*256 + j) * 256);
        float bd[NH];
        #pragma unroll
        for (int h = 0; h < NH; ++h) {
          bd[h] = __low2float(acc2[h]) + __high2float(acc2[h]);
          float4 k4 = kp[h*8 + cl];
          float4 q4 = *(const float4*)(qu + h*32 + cl*4);
          bd[h] += k4.x*q4.x + k4.y*q4.y + k4.z*q4.z + k4.w*q4.w;
        }
        #pragma unroll
        for (int h = 0; h < NH; ++h) {
          bd[h] += __shfl_xor(bd[h], 1);
          bd[h] += __shfl_xor(bd[h], 2);
          bd[h] += __shfl_xor(bd[h], 4);
        }
        if (cl == 0) {
          #pragma unroll
          for (int h = 0; h < NH; ++h) scl[h*32 + jl] = bd[h];
        }
        __syncthreads();
        { int h = tid >> 5, jj = tid & 31, j2 = jc * 32 + jj;
          if (j2 < rl) sc[h*256 + j2] = scl[h*32 + jj]; }
        __syncthreads();
      }
      // softmax
      {
        int h = tid >> 5, t = tid & 31;
        float mx = -INFINITY;
        #pragma unroll
        for (int m = 0; m < 8; ++m) mx = fmaxf(mx, sc[h*256 + t + 32*m]);
        #pragma unroll
        for (int sh = 16; sh >= 1; sh >>= 1) mx = fmaxf(mx, __shfl_xor(mx, sh));
        float sum = 0.f;
        #pragma unroll
        for (int m = 0; m < 8; ++m) {
          float e = __expf(sc[h*256 + t + 32*m] - mx);
          sc[h*256 + t + 32*m] = e;
          sum += e;
        }
        #pragma unroll
        for (int sh = 16; sh >= 1; sh >>= 1) sum += __shfl_xor(sum, sh);
        if (t == 0) inv8[h] = 1.f / sum;
      }
      __syncthreads();
      // AV
      {
        int n4 = tid & 63, jg = tid >> 6, h = n4 >> 3;
        float4 acc = make_float4(0.f, 0.f, 0.f, 0.f);
        if (jg * 64 < rl) {
          const float4* vp = (const float4*)(Vb + b * 65536) + n4;
          #pragma unroll 4
          for (int jj0 = 0; jj0 < 64; ++jj0) {
            int jj = jg * 64 + jj0;
            float s = sc[h*256 + jj];
            float4 v4 = vp[jj * 64];
            acc.x = fmaf(s, v4.x, acc.x); acc.y = fmaf(s, v4.y, acc.y);
            acc.z = fmaf(s, v4.z, acc.z); acc.w = fmaf(s, v4.w, acc.w);
          }
        }
        *(float4*)(part + jg*256 + n4*4) = acc;
      }
      __syncthreads();
      int n = tid;
      float o = part[n] + part[256+n] + part[512+n] + part[768+n];
      float val = cur[bi*256 + n] + o * inv8[n >> 5];
      ln_write(val, red2, Y + bi*256, tid);
      __syncthreads();
    }
    gbar(bar + (bc++) * BARSTRIDE, bid);

    // ================= ffn1: 512 units (128 rt4 x 4 colchunks) ==============
    for (int uu = bid; uu < 512; uu += NBLK) {
      int rt = uu >> 2, cc = uu & 3, r0 = rt * 4;
      float* ldsA = smem; float* red = smem + 1024;
      #pragma unroll
      for (int t = 0; t < 4; ++t) {
        int idx = t * 256 + tid, r = idx >> 8, c = idx & 255;
        ldsA[idx] = Y[(r0 + r) * 256 + c];
      }
      __syncthreads();
      gemm4((const float4*)w1 + cc * 64, 256, ldsA, red, tid);
      __syncthreads();
      int n = cc * 256 + tid;
      float bb = b1l[n];
      #pragma unroll
      for (int r = 0; r < 4; ++r)
        H1[(r0 + r) * 1024 + n] = fmaxf(bb + redsum(red, r, tid), 0.f);
      __syncthreads();
    }
    gbar(bar + (bc++) * BARSTRIDE, bid);

    // ================= ffn2 partials: 512 units (128 rt4 x 4 kchunks) =======
    for (int uu = bid; uu < 512; uu += NBLK) {
      int rt = uu >> 2, kc = uu & 3, r0 = rt * 4, k0 = kc * 256;
      float* ldsA = smem; float* red = smem + 1024;
      #pragma unroll
      for (int t = 0; t < 4; ++t) {
        int idx = t * 256 + tid, r = idx >> 8, c = idx & 255;
        ldsA[idx] = H1[(r0 + r) * 1024 + k0 + c];
      }
      __syncthreads();
      gemm4((const float4*)(w2 + k0 * 256), 64, ldsA, red, tid);
      __syncthreads();
      #pragma unroll
      for (int r = 0; r < 4; ++r)
        Pb[kc * 131072 + (r0 + r) * 256 + tid] = redsum(red, r, tid);
      __syncthreads();
    }
    gbar(bar + (bc++) * BARSTRIDE, bid);

    // ================= ffn2 reduce + relu + residual + LN : 512 units =======
    for (int uu = bid; uu < 512; uu += NBLK) {
      int m = uu;
      float* red2 = smem;
      float s = Pb[m*256 + tid] + Pb[131072 + m*256 + tid] +
                Pb[262144 + m*256 + tid] + Pb[393216 + m*256 + tid] + b2l[tid];
      float val = fmaxf(s, 0.f) + Y[m*256 + tid];
      ln_write(val, red2, outb + m*256, tid);
      __syncthreads();
    }
    gbar(bar + (bc++) * BARSTRIDE, bid);
  }
}

extern "C" void kernel_launch(void* const* d_in, const int* in_sizes, int n_in,
                              void* d_out, int out_size, void* d_ws, size_t ws_size,
                              hipStream_t stream) {
  const float* x            = (const float*)d_in[0];
  const int*   pos_s        = (const int*)d_in[1];
  const int*   pos_e        = (const int*)d_in[2];
  const int*   real_lengths = (const int*)d_in[3];
  const int*   lex_num      = (const int*)d_in[4];
  const float* pe           = (const float*)d_in[5];
  const float* W_fus        = (const float*)d_in[6];
  const float* b_fus        = (const float*)d_in[7];
  const float* Wq           = (const float*)d_in[8];
  const float* bq           = (const float*)d_in[9];
  const float* Wk           = (const float*)d_in[10];
  const float* bk           = (const float*)d_in[11];
  const float* Wv           = (const float*)d_in[12];
  const float* bv           = (const float*)d_in[13];
  const float* Wr           = (const float*)d_in[14];
  // br dropped: per-(b,i,h) constant score shift, softmax-invariant
  const float* u            = (const float*)d_in[16];
  const float* v            = (const float*)d_in[17];
  const float* W1           = (const float*)d_in[18];
  const float* b1           = (const float*)d_in[19];
  const float* W2           = (const float*)d_in[20];
  const float* b2           = (const float*)d_in[21];
  float* out = (float*)d_out;

  unsigned* bar = (unsigned*)d_ws;        // 16 barriers x 4096 uints = 256 KB
  float* base = (float*)d_ws + 16 * BARSTRIDE;
  __half* Tt = (__half*)base;             // 4*513*256 halfs = 262656 f32
  float* QU  = base + 262656;
  float* QV  = QU + 131072;
  float* Kb  = QV + 131072;
  float* Vb  = Kb + 131072;
  __half* P  = (__half*)(Vb + 131072);    // 512*2048 halfs = 524288 f32
  float* Y   = Vb + 131072 + 524288;
  float* C1  = Y + 131072;
  float* H1  = C1 + 131072;               // 524288
  float* Pb  = H1 + 524288;               // 524288

  hipMemsetAsync(bar, 0, 16 * BARSTRIDE * sizeof(unsigned), stream);
  k_mega<<<NBLK, NTHR, 0, stream>>>(x, pos_s, pos_e, real_lengths, lex_num, pe,
      W_fus, b_fus, Wq, bq, Wk, bk, Wv, bv, Wr, u, v, W1, b1, W2, b2, out,
      Tt, QU, QV, Kb, Vb, P, Y, C1, H1, Pb, bar);
}

// Round 9
// 106.496 us; speedup vs baseline: 20.2494x; 3.8636x over previous
//
#include <hip/hip_runtime.h>
#include <hip/hip_fp16.h>
#include <math.h>

#define NH 8
#define NDIST 513

union H8 { uint4 u4; __half2 h2[4]; };

// ---- 4 rows x 256 cols x 256 k GEMM partials (64cg x 4ks), red = [ks][r][c] ----
__device__ __forceinline__ void gemm4(const float4* __restrict__ w0, int ld4,
                                      const float* ldsA, float* red, int tid) {
  int cg = tid & 63, ks = tid >> 6;
  const float4* w = w0 + (ks * 64) * ld4 + cg;
  float a00=0,a01=0,a02=0,a03=0, a10=0,a11=0,a12=0,a13=0,
        a20=0,a21=0,a22=0,a23=0, a30=0,a31=0,a32=0,a33=0;
  const float* A = ldsA + ks * 64;
  #pragma unroll 4
  for (int kk = 0; kk < 64; ++kk) {
    float4 b4 = w[kk * ld4];
    float x0 = A[kk], x1 = A[256 + kk], x2 = A[512 + kk], x3 = A[768 + kk];
    a00=fmaf(x0,b4.x,a00); a01=fmaf(x0,b4.y,a01); a02=fmaf(x0,b4.z,a02); a03=fmaf(x0,b4.w,a03);
    a10=fmaf(x1,b4.x,a10); a11=fmaf(x1,b4.y,a11); a12=fmaf(x1,b4.z,a12); a13=fmaf(x1,b4.w,a13);
    a20=fmaf(x2,b4.x,a20); a21=fmaf(x2,b4.y,a21); a22=fmaf(x2,b4.z,a22); a23=fmaf(x2,b4.w,a23);
    a30=fmaf(x3,b4.x,a30); a31=fmaf(x3,b4.y,a31); a32=fmaf(x3,b4.z,a32); a33=fmaf(x3,b4.w,a33);
  }
  float* rp = red + ks * 1024 + cg * 4;
  *(float4*)(rp)       = make_float4(a00,a01,a02,a03);
  *(float4*)(rp + 256) = make_float4(a10,a11,a12,a13);
  *(float4*)(rp + 512) = make_float4(a20,a21,a22,a23);
  *(float4*)(rp + 768) = make_float4(a30,a31,a32,a33);
}

__device__ __forceinline__ float redsum(const float* red, int r, int c) {
  return red[r*256+c] + red[1024 + r*256+c] + red[2048 + r*256+c] + red[3072 + r*256+c];
}

__device__ __forceinline__ void ln_write(float val, float* red2, float* dst, int tid) {
  float ss = val;
  #pragma unroll
  for (int sh = 32; sh >= 1; sh >>= 1) ss += __shfl_xor(ss, sh);
  if ((tid & 63) == 0) red2[tid >> 6] = ss;
  __syncthreads();
  float mean = (red2[0] + red2[1] + red2[2] + red2[3]) * (1.f / 256.f);
  float d = val - mean;
  float s2 = d * d;
  __syncthreads();
  #pragma unroll
  for (int sh = 32; sh >= 1; sh >>= 1) s2 += __shfl_xor(s2, sh);
  if ((tid & 63) == 0) red2[tid >> 6] = s2;
  __syncthreads();
  float var = (red2[0] + red2[1] + red2[2] + red2[3]) * (1.f / 256.f);
  dst[tid] = d * rsqrtf(var + 1e-5f);
}

// ======== merged: tables (blocks 0..515) + layer-0 proj (blocks 516..899) ========
__global__ void k_t_proj(const float* __restrict__ pe, const float* __restrict__ W_fus,
                         const float* __restrict__ b_fus, const float* __restrict__ cur,
                         const float* __restrict__ Wq, const float* __restrict__ Wk,
                         const float* __restrict__ Wv, const float* __restrict__ bq,
                         const float* __restrict__ bk, const float* __restrict__ bv,
                         const float* __restrict__ uu, const float* __restrict__ vv,
                         __half* __restrict__ Tt, float* __restrict__ QU,
                         float* __restrict__ QV, float* __restrict__ Kb,
                         float* __restrict__ Vb) {
  __shared__ float smem[5120];
  float* ldsA = smem; float* red = smem + 1024;
  int tid = threadIdx.x, bx = blockIdx.x;
  if (bx < 516) {
    int g = bx & 3, r0 = (bx >> 2) * 4;
    #pragma unroll
    for (int t = 0; t < 4; ++t) {
      int idx = t * 256 + tid, r = idx >> 8, c = idx & 255;
      int row = r0 + r;
      ldsA[idx] = (row < NDIST) ? pe[row * 256 + c] : 0.f;
    }
    __syncthreads();
    gemm4((const float4*)(W_fus + g * 65536), 64, ldsA, red, tid);
    __syncthreads();
    float bb = (g == 0) ? b_fus[tid] : 0.f;
    #pragma unroll
    for (int r = 0; r < 4; ++r) {
      int row = r0 + r;
      if (row < NDIST)
        Tt[(g * NDIST + row) * 256 + tid] = __float2half(bb + redsum(red, r, tid));
    }
  } else {
    int pb = bx - 516;
    int by = pb / 128, r0 = (pb % 128) * 4;
    const float* W = (by == 0) ? Wq : (by == 1) ? Wk : Wv;
    #pragma unroll
    for (int t = 0; t < 4; ++t) {
      int idx = t * 256 + tid, r = idx >> 8, c = idx & 255;
      ldsA[idx] = cur[(r0 + r) * 256 + c];
    }
    __syncthreads();
    gemm4((const float4*)W, 64, ldsA, red, tid);
    __syncthreads();
    #pragma unroll
    for (int r = 0; r < 4; ++r) {
      int row = r0 + r;
      float s = redsum(red, r, tid);
      if (by == 0) {
        float base = s + bq[tid];
        QU[row * 256 + tid] = base + uu[tid];
        QV[row * 256 + tid] = base + vv[tid];
      } else if (by == 1) {
        Kb[row * 256 + tid] = s + bk[tid];
      } else {
        Vb[row * 256 + tid] = s + bv[tid];
      }
    }
  }
}

// ======== layer-1 projections ; grid (128, 3), 4 rows/block ========
__global__ void k_proj(const float* __restrict__ cur, const float* __restrict__ Wq,
                       const float* __restrict__ Wk, const float* __restrict__ Wv,
                       const float* __restrict__ bq, const float* __restrict__ bk,
                       const float* __restrict__ bv, const float* __restrict__ uu,
                       const float* __restrict__ vv, float* __restrict__ QU,
                       float* __restrict__ QV, float* __restrict__ Kb,
                       float* __restrict__ Vb) {
  __shared__ float smem[5120];
  float* ldsA = smem; float* red = smem + 1024;
  int tid = threadIdx.x;
  int r0 = blockIdx.x * 4;
  int by = blockIdx.y;
  const float* W = (by == 0) ? Wq : (by == 1) ? Wk : Wv;
  #pragma unroll
  for (int t = 0; t < 4; ++t) {
    int idx = t * 256 + tid, r = idx >> 8, c = idx & 255;
    ldsA[idx] = cur[(r0 + r) * 256 + c];
  }
  __syncthreads();
  gemm4((const float4*)W, 64, ldsA, red, tid);
  __syncthreads();
  #pragma unroll
  for (int r = 0; r < 4; ++r) {
    int row = r0 + r;
    float s = redsum(red, r, tid);
    if (by == 0) {
      float base = s + bq[tid];
      QU[row * 256 + tid] = base + uu[tid];
      QV[row * 256 + tid] = base + vv[tid];
    } else if (by == 1) {
      Kb[row * 256 + tid] = s + bk[tid];
    } else {
      Vb[row * 256 + tid] = s + bv[tid];
    }
  }
}

// ======== P[bi][h*256+c] (f16) ; grid (128 rowtiles, 8 heads), 4 rows ========
__global__ void k_p(const float* __restrict__ QV, const float* __restrict__ Wr,
                    __half* __restrict__ P) {
  __shared__ float ldsB[32 * 257];
  __shared__ float ldsA[4 * 32];
  int rt = blockIdx.x, h = blockIdx.y, tid = threadIdx.x;
  int r0 = rt * 4;
  #pragma unroll
  for (int pass = 0; pass < 8; ++pass) {
    int c = pass * 32 + (tid >> 3), q = tid & 7;
    float4 w4 = ((const float4*)(Wr + c * 256 + h * 32))[q];
    ldsB[(q*4+0)*257 + c] = w4.x; ldsB[(q*4+1)*257 + c] = w4.y;
    ldsB[(q*4+2)*257 + c] = w4.z; ldsB[(q*4+3)*257 + c] = w4.w;
  }
  if (tid < 128) {
    int r = tid >> 5, d = tid & 31;
    ldsA[r * 32 + d] = QV[(r0 + r) * 256 + h * 32 + d];
  }
  __syncthreads();
  int c = tid;
  float acc[4] = {0, 0, 0, 0};
  #pragma unroll 4
  for (int d = 0; d < 32; ++d) {
    float b = ldsB[d * 257 + c];
    #pragma unroll
    for (int r = 0; r < 4; ++r) acc[r] = fmaf(ldsA[r * 32 + d], b, acc[r]);
  }
  #pragma unroll
  for (int r = 0; r < 4; ++r) P[(r0 + r) * 2048 + h * 256 + c] = __float2half(acc[r]);
}

// ======== fused score + softmax + AV + residual + LN ; grid 512, block 256 ====
__global__ void k_attn(const float* __restrict__ QU, const float* __restrict__ Kb,
                       const float* __restrict__ Vb, const __half* __restrict__ P,
                       const __half* __restrict__ Tt, const float* __restrict__ cur,
                       const int* __restrict__ pos_s, const int* __restrict__ pos_e,
                       const int* __restrict__ real_lengths, const int* __restrict__ lex_num,
                       float* __restrict__ Y) {
  __shared__ __align__(16) float smem[4640];
  int tid = threadIdx.x;
  int bi = blockIdx.x, b = bi >> 8, i = bi & 255;
  int rl = real_lengths[b] + lex_num[0];
  float* sc    = smem;                     // 2048
  __half* plh  = (__half*)(smem + 2048);   // 2048 halfs
  float* qu    = smem + 3072;              // 256
  float* part  = smem + 3328;              // 1024
  float* inv8  = smem + 4352;              // 8
  float* red2  = smem + 4360;              // 4
  float* scl   = smem + 4368;              // 256
  #pragma unroll
  for (int t = 0; t < 8; ++t) sc[t * 256 + tid] = -1e15f;
  ((uint4*)plh)[tid] = ((const uint4*)(P + bi * 2048))[tid];
  qu[tid] = QU[bi * 256 + tid];
  __syncthreads();
  int psi = pos_s[b*256 + i], pei = pos_e[b*256 + i];
  int jl = tid >> 3, cl = tid & 7;
  int nchunk = (rl + 31) >> 5;
  for (int jc = 0; jc < nchunk; ++jc) {
    int j = jc * 32 + jl;
    int psj = pos_s[b*256 + j], pej = pos_e[b*256 + j];
    const __half* t0 = Tt + (psi - psj + 256) * 256;
    const __half* t1 = Tt + (NDIST   + (psi - pej + 256)) * 256;
    const __half* t2 = Tt + (2*NDIST + (pei - psj + 256)) * 256;
    const __half* t3 = Tt + (3*NDIST + (pei - pej + 256)) * 256;
    __half2 z2 = __float2half2_rn(0.f);
    __half2 acc2[NH];
    #pragma unroll
    for (int h = 0; h < NH; ++h) acc2[h] = z2;
    #pragma unroll
    for (int ci = 0; ci < 4; ++ci) {
      int c0 = (ci * 8 + cl) * 8;
      H8 A0, A1, A2, A3;
      A0.u4 = *(const uint4*)(t0 + c0);
      A1.u4 = *(const uint4*)(t1 + c0);
      A2.u4 = *(const uint4*)(t2 + c0);
      A3.u4 = *(const uint4*)(t3 + c0);
      __half2 r2[4];
      #pragma unroll
      for (int p = 0; p < 4; ++p) {
        __half2 s = __hadd2(__hadd2(A0.h2[p], A1.h2[p]), __hadd2(A2.h2[p], A3.h2[p]));
        r2[p] = __hmul2(s, __hgt2(s, z2));
      }
      #pragma unroll
      for (int h = 0; h < NH; ++h) {
        H8 Ph;
        Ph.u4 = *(const uint4*)(plh + h*256 + c0);
        #pragma unroll
        for (int p = 0; p < 4; ++p) acc2[h] = __hfma2(r2[p], Ph.h2[p], acc2[h]);
      }
    }
    const float4* kp = (const float4*)(Kb + (b*256 + j) * 256);
    float bd[NH];
    #pragma unroll
    for (int h = 0; h < NH; ++h) {
      bd[h] = __low2float(acc2[h]) + __high2float(acc2[h]);
      float4 k4 = kp[h*8 + cl];
      float4 q4 = *(const float4*)(qu + h*32 + cl*4);
      bd[h] += k4.x*q4.x + k4.y*q4.y + k4.z*q4.z + k4.w*q4.w;
    }
    #pragma unroll
    for (int h = 0; h < NH; ++h) {
      bd[h] += __shfl_xor(bd[h], 1);
      bd[h] += __shfl_xor(bd[h], 2);
      bd[h] += __shfl_xor(bd[h], 4);
    }
    if (cl == 0) {
      #pragma unroll
      for (int h = 0; h < NH; ++h) scl[h*32 + jl] = bd[h];
    }
    __syncthreads();
    { int h = tid >> 5, jj = tid & 31, j2 = jc * 32 + jj;
      if (j2 < rl) sc[h*256 + j2] = scl[h*32 + jj]; }
    __syncthreads();
  }
  // softmax
  {
    int h = tid >> 5, t = tid & 31;
    float mx = -INFINITY;
    #pragma unroll
    for (int m = 0; m < 8; ++m) mx = fmaxf(mx, sc[h*256 + t + 32*m]);
    #pragma unroll
    for (int sh = 16; sh >= 1; sh >>= 1) mx = fmaxf(mx, __shfl_xor(mx, sh));
    float sum = 0.f;
    #pragma unroll
    for (int m = 0; m < 8; ++m) {
      float e = __expf(sc[h*256 + t + 32*m] - mx);
      sc[h*256 + t + 32*m] = e;
      sum += e;
    }
    #pragma unroll
    for (int sh = 16; sh >= 1; sh >>= 1) sum += __shfl_xor(sum, sh);
    if (t == 0) inv8[h] = 1.f / sum;
  }
  __syncthreads();
  // AV
  {
    int n4 = tid & 63, jg = tid >> 6, h = n4 >> 3;
    float4 acc = make_float4(0.f, 0.f, 0.f, 0.f);
    if (jg * 64 < rl) {
      const float4* vp = (const float4*)(Vb + b * 65536) + n4;
      #pragma unroll 4
      for (int jj0 = 0; jj0 < 64; ++jj0) {
        int jj = jg * 64 + jj0;
        float s = sc[h*256 + jj];
        float4 v4 = vp[jj * 64];
        acc.x = fmaf(s, v4.x, acc.x); acc.y = fmaf(s, v4.y, acc.y);
        acc.z = fmaf(s, v4.z, acc.z); acc.w = fmaf(s, v4.w, acc.w);
      }
    }
    *(float4*)(part + jg*256 + n4*4) = acc;
  }
  __syncthreads();
  int n = tid;
  float o = part[n] + part[256+n] + part[512+n] + part[768+n];
  float val = cur[bi*256 + n] + o * inv8[n >> 5];
  ln_write(val, red2, Y + bi*256, tid);
}

// ======== FFN1: relu(Y@W1+b1) ; grid (128, 4 colchunks), 4 rows ========
__global__ void k_ffn1(const float* __restrict__ Y, const float* __restrict__ W1,
                       const float* __restrict__ b1, float* __restrict__ H1) {
  __shared__ float smem[5120];
  float* ldsA = smem; float* red = smem + 1024;
  int tid = threadIdx.x;
  int r0 = blockIdx.x * 4, by = blockIdx.y;
  #pragma unroll
  for (int t = 0; t < 4; ++t) {
    int idx = t * 256 + tid, r = idx >> 8, c = idx & 255;
    ldsA[idx] = Y[(r0 + r) * 256 + c];
  }
  __syncthreads();
  gemm4((const float4*)W1 + by * 64, 256, ldsA, red, tid);
  __syncthreads();
  int n = by * 256 + tid;
  float bb = b1[n];
  #pragma unroll
  for (int r = 0; r < 4; ++r)
    H1[(r0 + r) * 1024 + n] = fmaxf(bb + redsum(red, r, tid), 0.f);
}

// ======== FFN2 partials: grid (128 rowtiles, 4 kchunks), 4 rows ========
__global__ void k_ffn2(const float* __restrict__ H1, const float* __restrict__ W2,
                       float* __restrict__ Pbuf) {
  __shared__ float smem[5120];
  float* ldsA = smem; float* red = smem + 1024;
  int tid = threadIdx.x;
  int r0 = blockIdx.x * 4, kc = blockIdx.y, k0 = kc * 256;
  #pragma unroll
  for (int t = 0; t < 4; ++t) {
    int idx = t * 256 + tid, r = idx >> 8, c = idx & 255;
    ldsA[idx] = H1[(r0 + r) * 1024 + k0 + c];
  }
  __syncthreads();
  gemm4((const float4*)(W2 + k0 * 256), 64, ldsA, red, tid);
  __syncthreads();
  #pragma unroll
  for (int r = 0; r < 4; ++r)
    Pbuf[kc * 131072 + (r0 + r) * 256 + tid] = redsum(red, r, tid);
}

// ======== FFN2 reduce + relu + residual + LN ; grid 512, block 256 ========
__global__ void k_ffn2red_ln(const float* __restrict__ Pbuf, const float* __restrict__ b2,
                             const float* __restrict__ Y, float* __restrict__ O) {
  __shared__ float red2[4];
  int m = blockIdx.x, tid = threadIdx.x;
  float s = Pbuf[m * 256 + tid] + Pbuf[131072 + m * 256 + tid] +
            Pbuf[262144 + m * 256 + tid] + Pbuf[393216 + m * 256 + tid] + b2[tid];
  float val = fmaxf(s, 0.f) + Y[m * 256 + tid];
  ln_write(val, red2, O + m * 256, tid);
}

extern "C" void kernel_launch(void* const* d_in, const int* in_sizes, int n_in,
                              void* d_out, int out_size, void* d_ws, size_t ws_size,
                              hipStream_t stream) {
  const float* x            = (const float*)d_in[0];
  const int*   pos_s        = (const int*)d_in[1];
  const int*   pos_e        = (const int*)d_in[2];
  const int*   real_lengths = (const int*)d_in[3];
  const int*   lex_num      = (const int*)d_in[4];
  const float* pe           = (const float*)d_in[5];
  const float* W_fus        = (const float*)d_in[6];
  const float* b_fus        = (const float*)d_in[7];
  const float* Wq           = (const float*)d_in[8];
  const float* bq           = (const float*)d_in[9];
  const float* Wk           = (const float*)d_in[10];
  const float* bk           = (const float*)d_in[11];
  const float* Wv           = (const float*)d_in[12];
  const float* bv           = (const float*)d_in[13];
  const float* Wr           = (const float*)d_in[14];
  // br dropped: per-(b,i,h) constant score shift, softmax-invariant
  const float* u            = (const float*)d_in[16];
  const float* v            = (const float*)d_in[17];
  const float* W1           = (const float*)d_in[18];
  const float* b1           = (const float*)d_in[19];
  const float* W2           = (const float*)d_in[20];
  const float* b2           = (const float*)d_in[21];
  float* out = (float*)d_out;

  float* ws = (float*)d_ws;
  __half* Tt = (__half*)ws;                 // 525312 halfs = 262656 f32
  float* QU  = ws + 262656;
  float* QV  = QU + 131072;
  float* Kb  = QV + 131072;
  float* Vb  = Kb + 131072;
  __half* P  = (__half*)(Vb + 131072);      // 524288 f32
  float* Y   = Vb + 131072 + 524288;
  float* C1  = Y + 131072;
  float* H1  = C1 + 131072;                 // 524288
  float* Pb  = H1 + 524288;                 // 524288

  // tables + layer-0 projections in one dispatch (independent work)
  k_t_proj<<<900, 256, 0, stream>>>(pe, W_fus, b_fus, x, Wq, Wk, Wv, bq, bk, bv,
                                    u, v, Tt, QU, QV, Kb, Vb);

  for (int l = 0; l < 2; ++l) {
    const float* cur = l ? C1 : x;
    float* outb = l ? out : C1;
    const int wo = l * 65536, bo = l * 256;
    if (l == 1)
      k_proj<<<dim3(128, 3), 256, 0, stream>>>(cur, Wq + wo, Wk + wo, Wv + wo,
                                               bq + bo, bk + bo, bv + bo, u + bo, v + bo,
                                               QU, QV, Kb, Vb);
    k_p<<<dim3(128, 8), 256, 0, stream>>>(QV, Wr + wo, P);
    k_attn<<<512, 256, 0, stream>>>(QU, Kb, Vb, P, Tt, cur, pos_s, pos_e,
                                    real_lengths, lex_num, Y);
    k_ffn1<<<dim3(128, 4), 256, 0, stream>>>(Y, W1 + l * 262144, b1 + l * 1024, H1);
    k_ffn2<<<dim3(128, 4), 256, 0, stream>>>(H1, W2 + l * 262144, Pb);
    k_ffn2red_ln<<<512, 256, 0, stream>>>(Pb, b2 + bo, Y, outb);
  }
}